// Round 6
// baseline (294.824 us; speedup 1.0000x reference)
//
#include <hip/hip_runtime.h>
#include <hip/hip_bf16.h>

typedef __bf16 bf16x8 __attribute__((ext_vector_type(8)));
typedef float  float4v __attribute__((ext_vector_type(4)));
typedef unsigned short u16;
typedef u16 u16x8 __attribute__((ext_vector_type(8)));

#define NB 32
#define NT 2048
#define ND 512
#define NU 512
#define BK 64        // K per phase; 8 phases

__device__ __forceinline__ u16 f2bf(float f) {
    union { float f; unsigned u; } v; v.f = f;
    unsigned u = v.u;
    return (u16)((u + 0x7fffu + ((u >> 16) & 1u)) >> 16);  // RNE
}

__device__ __forceinline__ u16x8 cvt8(float4v a, float4v b) {
    union { __hip_bfloat162 h[4]; u16x8 v; } u;
    u.h[0] = __float22bfloat162_rn(make_float2(a[0], a[1]));
    u.h[1] = __float22bfloat162_rn(make_float2(a[2], a[3]));
    u.h[2] = __float22bfloat162_rn(make_float2(b[0], b[1]));
    u.h[3] = __float22bfloat162_rn(make_float2(b[2], b[3]));
    return u.v;
}

__device__ __forceinline__ float fast_tanh(float x) {
    float e = __expf(-2.f * x);
    return 2.f / (1.f + e) - 1.f;
}

// ---- prep: W1->bf16 W1^T, projh, zero logits/ctx ---------------------------
__global__ void k_prep(const float* __restrict__ W1, u16* __restrict__ w1t,
                       const float* __restrict__ hidden, const float* __restrict__ W2,
                       const float* __restrict__ b2, float* __restrict__ projh,
                       float* __restrict__ logits, float* __restrict__ ctx) {
    __shared__ u16 tile[32][33];
    __shared__ float h[ND];
    __shared__ float part[4][64];
    if (threadIdx.x < 128) logits[blockIdx.x * 128 + threadIdx.x] = 0.f;
    else if (threadIdx.x < 160) ctx[blockIdx.x * 32 + (threadIdx.x - 128)] = 0.f;

    if (blockIdx.x < 256) {
        int bd = (blockIdx.x & 15) * 32;
        int bu = (blockIdx.x >> 4) * 32;
        int tx = threadIdx.x & 31, ty = threadIdx.x >> 5;
        #pragma unroll
        for (int i = 0; i < 4; ++i)
            tile[ty + i * 8][tx] = f2bf(W1[(bd + ty + i * 8) * NU + bu + tx]);
        __syncthreads();
        #pragma unroll
        for (int i = 0; i < 4; ++i)
            w1t[(bu + ty + i * 8) * ND + bd + tx] = tile[tx][ty + i * 8];
    } else {
        int blk = blockIdx.x - 256;
        int b  = blk >> 3;
        int uc = (blk & 7) * 64;
        int ui = threadIdx.x & 63;
        int du = threadIdx.x >> 6;
        for (int i = threadIdx.x; i < ND; i += 256) h[i] = hidden[b * ND + i];
        __syncthreads();
        int u = uc + ui;
        float acc = 0.f;
        int d0 = du * 128;
        #pragma unroll 8
        for (int d = 0; d < 128; ++d) acc += h[d0 + d] * W2[(d0 + d) * NU + u];
        part[du][ui] = acc;
        __syncthreads();
        if (threadIdx.x < 64)
            projh[b * NU + u] = part[0][ui] + part[1][ui] + part[2][ui] + part[3][ui] + b2[u];
    }
}

// ---- conv: features fp32 -> bf16 (streaming) -------------------------------
__global__ void k_conv(const float* __restrict__ feat, u16* __restrict__ fbf) {
    long g = ((long)blockIdx.x * 256 + threadIdx.x) * 8;
    float4v f0 = *(const float4v*)(feat + g);
    float4v f1 = *(const float4v*)(feat + g + 4);
    *(u16x8*)(fbf + g) = cvt8(f0, f1);
}

// ---- logits (bf16 path): 128 rows x 128 U per block, K=512, 8 phases -------
// m97 structure: both tiles via global_load_lds (16B/lane), 2-barrier K-loop,
// 32 KB LDS single-buffered -> 4 blocks/CU. XOR chunk swizzle (R3-verified 0
// conflicts). 4 waves in 2x2: wave = 64 rows x 64 U (mt4 x nt4, acc 64).
__global__ __launch_bounds__(256, 4)
void k_logits_bf(const u16* __restrict__ fbf, const u16* __restrict__ w1t,
                 const float* __restrict__ b1, const float* __restrict__ projh,
                 const float* __restrict__ V, float* __restrict__ logits) {
    __shared__ __align__(16) u16 aT[128 * BK];   // 16 KB
    __shared__ __align__(16) u16 bT[128 * BK];   // 16 KB

    const int mtile = blockIdx.x >> 2;
    const int utile = blockIdx.x & 3;            // consecutive blocks share A rows
    const int row0  = mtile * 128;
    const int uc    = utile * 128;
    const int b     = row0 >> 11;
    const int tid   = threadIdx.x;
    const int wave  = tid >> 6, lane = tid & 63;
    const int quad  = lane >> 4, col = lane & 15;
    const int wr    = wave >> 1, wc = wave & 1;

    float4v acc[4][4];
    #pragma unroll
    for (int mt = 0; mt < 4; ++mt)
        #pragma unroll
        for (int nt = 0; nt < 4; ++nt) acc[mt][nt] = (float4v)0.f;

    const u16* abase = fbf + (long)row0 * ND;
    const u16* wbase = w1t + uc * ND;

    for (int p = 0; p < 8; ++p) {
        const int k0 = p * BK;
        // stage A: 128 rows x 64 k, 1024 16B slots, pure DMA
        #pragma unroll
        for (int j = 0; j < 4; ++j) {
            int s  = j * 256 + tid;
            int r  = s >> 3;
            int gc = (s & 7) ^ (r & 7);
            const u16* gp = abase + (long)r * ND + k0 + gc * 8;
            u16* lp = &aT[(j * 256 + wave * 64) * 8];
            __builtin_amdgcn_global_load_lds(
                (const __attribute__((address_space(1))) unsigned int*)gp,
                (__attribute__((address_space(3))) unsigned int*)lp, 16, 0, 0);
        }
        // stage B: 128 rows x 64 k
        #pragma unroll
        for (int j = 0; j < 4; ++j) {
            int s  = j * 256 + tid;
            int r  = s >> 3;
            int gc = (s & 7) ^ (r & 7);
            const u16* gp = wbase + (long)r * ND + k0 + gc * 8;
            u16* lp = &bT[(j * 256 + wave * 64) * 8];
            __builtin_amdgcn_global_load_lds(
                (const __attribute__((address_space(1))) unsigned int*)gp,
                (__attribute__((address_space(3))) unsigned int*)lp, 16, 0, 0);
        }
        __syncthreads();

        #pragma unroll
        for (int ks = 0; ks < 2; ++ks) {
            bf16x8 af[4], bf[4];
            #pragma unroll
            for (int mt = 0; mt < 4; ++mt) {
                int ra = wr * 64 + mt * 16 + col;
                af[mt] = *(const bf16x8*)(&aT[ra * BK + (((ks * 4 + quad) ^ (ra & 7)) * 8)]);
            }
            #pragma unroll
            for (int nt = 0; nt < 4; ++nt) {
                int rb = wc * 64 + nt * 16 + col;
                bf[nt] = *(const bf16x8*)(&bT[rb * BK + (((ks * 4 + quad) ^ (rb & 7)) * 8)]);
            }
            #pragma unroll
            for (int nt = 0; nt < 4; ++nt)
                #pragma unroll
                for (int mt = 0; mt < 4; ++mt)
                    acc[mt][nt] = __builtin_amdgcn_mfma_f32_16x16x32_bf16(af[mt], bf[nt], acc[mt][nt], 0, 0, 0);
        }
        __syncthreads();
    }

    // epilogue: u = uc + wc*64 + nt*16 + col; row = row0 + wr*64 + mt*16 + quad*4 + rg
    float b1v[4], phv[4], Vv[4];
    #pragma unroll
    for (int nt = 0; nt < 4; ++nt) {
        int u = uc + wc * 64 + nt * 16 + col;
        b1v[nt] = b1[u];
        phv[nt] = projh[b * NU + u];
        Vv[nt]  = V[u];
    }

    float (*part)[128] = (float(*)[128])aT;   // [2][128] reuse, post-barrier
    #pragma unroll
    for (int mt = 0; mt < 4; ++mt) {
        #pragma unroll
        for (int rg = 0; rg < 4; ++rg) {
            float s = 0.f;
            #pragma unroll
            for (int nt = 0; nt < 4; ++nt) {
                float pv = acc[mt][nt][rg] + b1v[nt] + phv[nt];
                s += fast_tanh(pv) * Vv[nt];
            }
            s += __shfl_xor(s, 1);
            s += __shfl_xor(s, 2);
            s += __shfl_xor(s, 4);
            s += __shfl_xor(s, 8);
            if (col == 0) part[wc][wr * 64 + mt * 16 + quad * 4 + rg] = s;
        }
    }
    __syncthreads();
    if (tid < 128)
        atomicAdd(&logits[row0 + tid], part[0][tid] + part[1][tid]);
}

// ---- logits fallback (R3-proven fp32-staging path, 87 us) ------------------
__global__ __launch_bounds__(256, 4)
void k_logits_f32(const float* __restrict__ feat, const u16* __restrict__ w1t,
                  const float* __restrict__ b1, const float* __restrict__ projh,
                  const float* __restrict__ V, float* __restrict__ logits) {
    __shared__ __align__(16) u16 aT[64 * BK];
    __shared__ __align__(16) u16 bT[256 * BK];

    const int mtile = blockIdx.x & 1023;
    const int utile = blockIdx.x >> 10;
    const int row0  = mtile * 64;
    const int uc    = utile * 256;
    const int b     = row0 >> 11;
    const int tid   = threadIdx.x;
    const int wave  = tid >> 6, lane = tid & 63;
    const int quad  = lane >> 4, col = lane & 15;

    float4v acc[4][4];
    #pragma unroll
    for (int mt = 0; mt < 4; ++mt)
        #pragma unroll
        for (int nt = 0; nt < 4; ++nt) acc[mt][nt] = (float4v)0.f;

    const float* fbase = feat + (long)row0 * ND;
    const u16*   wbase = w1t + uc * ND;

    for (int p = 0; p < 8; ++p) {
        const int k0 = p * BK;
        #pragma unroll
        for (int i = 0; i < 2; ++i) {
            int s = tid + i * 256;
            int r = s >> 3, c = s & 7;
            const float* gp = fbase + (long)r * ND + k0 + c * 8;
            float4v f0 = *(const float4v*)gp;
            float4v f1 = *(const float4v*)(gp + 4);
            *(u16x8*)(&aT[r * BK + ((c ^ (r & 7)) * 8)]) = cvt8(f0, f1);
        }
        #pragma unroll
        for (int j = 0; j < 8; ++j) {
            int s  = j * 256 + tid;
            int r  = s >> 3;
            int gc = (s & 7) ^ (r & 7);
            const u16* gp = wbase + (long)r * ND + k0 + gc * 8;
            u16* lp = &bT[(j * 256 + wave * 64) * 8];
            __builtin_amdgcn_global_load_lds(
                (const __attribute__((address_space(1))) unsigned int*)gp,
                (__attribute__((address_space(3))) unsigned int*)lp, 16, 0, 0);
        }
        __syncthreads();

        #pragma unroll
        for (int ks = 0; ks < 2; ++ks) {
            bf16x8 af[4], bf[4];
            #pragma unroll
            for (int mt = 0; mt < 4; ++mt) {
                int ra = mt * 16 + col;
                af[mt] = *(const bf16x8*)(&aT[ra * BK + (((ks * 4 + quad) ^ (ra & 7)) * 8)]);
            }
            #pragma unroll
            for (int nt = 0; nt < 4; ++nt) {
                int rb = wave * 64 + nt * 16 + col;
                bf[nt] = *(const bf16x8*)(&bT[rb * BK + (((ks * 4 + quad) ^ (rb & 7)) * 8)]);
            }
            #pragma unroll
            for (int nt = 0; nt < 4; ++nt)
                #pragma unroll
                for (int mt = 0; mt < 4; ++mt)
                    acc[mt][nt] = __builtin_amdgcn_mfma_f32_16x16x32_bf16(af[mt], bf[nt], acc[mt][nt], 0, 0, 0);
        }
        __syncthreads();
    }

    float b1v[4], phv[4], Vv[4];
    #pragma unroll
    for (int nt = 0; nt < 4; ++nt) {
        int u = uc + wave * 64 + nt * 16 + col;
        b1v[nt] = b1[u];
        phv[nt] = projh[b * NU + u];
        Vv[nt]  = V[u];
    }
    float (*partial)[64] = (float(*)[64])aT;
    #pragma unroll
    for (int mt = 0; mt < 4; ++mt) {
        #pragma unroll
        for (int rg = 0; rg < 4; ++rg) {
            float s = 0.f;
            #pragma unroll
            for (int nt = 0; nt < 4; ++nt) {
                float pv = acc[mt][nt][rg] + b1v[nt] + phv[nt];
                s += fast_tanh(pv) * Vv[nt];
            }
            s += __shfl_xor(s, 1);
            s += __shfl_xor(s, 2);
            s += __shfl_xor(s, 4);
            s += __shfl_xor(s, 8);
            if (col == 0) partial[wave][mt * 16 + quad * 4 + rg] = s;
        }
    }
    __syncthreads();
    if (tid < 64) {
        float v = partial[0][tid] + partial[1][tid] + partial[2][tid] + partial[3][tid];
        atomicAdd(&logits[row0 + tid], v);
    }
}

// ---- fused softmax + context (fp32 features for accuracy) ------------------
__global__ void k_ctx(const float* __restrict__ feat, const float* __restrict__ logits,
                      float* __restrict__ attn, float* __restrict__ ctx) {
    const int b  = blockIdx.x >> 4;
    const int tc = blockIdx.x & 15;
    const int tid = threadIdx.x;
    __shared__ float wm[4], ws[4];
    __shared__ float sa[128];

    const float* lg = logits + b * NT;
    float lv[8];
    float m = -1e30f;
    #pragma unroll
    for (int i = 0; i < 8; ++i) { lv[i] = lg[tid + i * 256]; m = fmaxf(m, lv[i]); }
    for (int o = 1; o < 64; o <<= 1) m = fmaxf(m, __shfl_xor(m, o));
    if ((tid & 63) == 0) wm[tid >> 6] = m;
    __syncthreads();
    m = fmaxf(fmaxf(wm[0], wm[1]), fmaxf(wm[2], wm[3]));
    float ssum = 0.f;
    #pragma unroll
    for (int i = 0; i < 8; ++i) ssum += __expf(lv[i] - m);
    for (int o = 1; o < 64; o <<= 1) ssum += __shfl_xor(ssum, o);
    if ((tid & 63) == 0) ws[tid >> 6] = ssum;
    __syncthreads();
    float inv = 1.f / (ws[0] + ws[1] + ws[2] + ws[3]);

    if (tid < 128) {
        int t = tc * 128 + tid;
        float a = __expf(lg[t] - m) * inv;
        sa[tid] = a;
        attn[b * NT + t] = a;
    }
    __syncthreads();

    const float* fb = feat + ((long)b * NT + tc * 128) * ND + tid * 2;
    float ax = 0.f, ay = 0.f;
    #pragma unroll 16
    for (int t = 0; t < 128; ++t) {
        float a = sa[t];
        float2 f = *(const float2*)(fb + (long)t * ND);
        ax += a * f.x; ay += a * f.y;
    }
    atomicAdd(&ctx[b * ND + tid * 2],     ax);
    atomicAdd(&ctx[b * ND + tid * 2 + 1], ay);
}

extern "C" void kernel_launch(void* const* d_in, const int* in_sizes, int n_in,
                              void* d_out, int out_size, void* d_ws, size_t ws_size,
                              hipStream_t stream) {
    const float* feat   = (const float*)d_in[0];
    const float* hidden = (const float*)d_in[1];
    const float* W1     = (const float*)d_in[2];
    const float* b1     = (const float*)d_in[3];
    const float* W2     = (const float*)d_in[4];
    const float* b2     = (const float*)d_in[5];
    const float* V      = (const float*)d_in[6];
    // d_in[7] = bv: unused — softmax(x + bv) == softmax(x)

    float* out_ctx  = (float*)d_out;            // [32,512]
    float* out_attn = (float*)d_out + NB * ND;  // [32,2048,1]

    u16*   w1t    = (u16*)d_ws;                                          // 512 KB
    float* projh  = (float*)((char*)d_ws + 512 * 1024);                  // 64 KB
    float* logits = (float*)((char*)d_ws + 512 * 1024 + 64 * 1024);      // 256 KB
    u16*   fbf    = (u16*)((char*)d_ws + (1 << 20));                     // 64 MB

    const size_t need = (size_t)(1 << 20) + (size_t)NB * NT * ND * 2;

    k_prep<<<512, 256, 0, stream>>>(W1, w1t, hidden, W2, b2, projh, logits, out_ctx);
    if (ws_size >= need) {
        k_conv     <<<16384, 256, 0, stream>>>(feat, fbf);
        k_logits_bf<<<2048, 256, 0, stream>>>(fbf, w1t, b1, projh, V, logits);
    } else {
        k_logits_f32<<<2048, 256, 0, stream>>>(feat, w1t, b1, projh, V, logits);
    }
    k_ctx<<<512, 256, 0, stream>>>(feat, logits, out_attn, out_ctx);
}

// Round 7
// 272.720 us; speedup vs baseline: 1.0810x; 1.0810x over previous
//
#include <hip/hip_runtime.h>
#include <hip/hip_bf16.h>

typedef __bf16 bf16x8 __attribute__((ext_vector_type(8)));
typedef float  float4v __attribute__((ext_vector_type(4)));
typedef unsigned short u16;
typedef u16 u16x8 __attribute__((ext_vector_type(8)));

#define NB 32
#define NT 2048
#define ND 512
#define NU 512
#define BK 64        // K per phase; 8 phases

__device__ __forceinline__ u16 f2bf(float f) {
    union { float f; unsigned u; } v; v.f = f;
    unsigned u = v.u;
    return (u16)((u + 0x7fffu + ((u >> 16) & 1u)) >> 16);  // RNE
}

__device__ __forceinline__ u16x8 cvt8(float4v a, float4v b) {
    union { __hip_bfloat162 h[4]; u16x8 v; } u;
    u.h[0] = __float22bfloat162_rn(make_float2(a[0], a[1]));
    u.h[1] = __float22bfloat162_rn(make_float2(a[2], a[3]));
    u.h[2] = __float22bfloat162_rn(make_float2(b[0], b[1]));
    u.h[3] = __float22bfloat162_rn(make_float2(b[2], b[3]));
    return u.v;
}

__device__ __forceinline__ float fast_tanh(float x) {
    float e = __expf(-2.f * x);
    return 2.f / (1.f + e) - 1.f;
}

// ---- prep: W1->bf16 W1^T, projh, zero logits/ctx ---------------------------
__global__ void k_prep(const float* __restrict__ W1, u16* __restrict__ w1t,
                       const float* __restrict__ hidden, const float* __restrict__ W2,
                       const float* __restrict__ b2, float* __restrict__ projh,
                       float* __restrict__ logits, float* __restrict__ ctx) {
    __shared__ u16 tile[32][33];
    __shared__ float h[ND];
    __shared__ float part[4][64];
    if (threadIdx.x < 128) logits[blockIdx.x * 128 + threadIdx.x] = 0.f;
    else if (threadIdx.x < 160) ctx[blockIdx.x * 32 + (threadIdx.x - 128)] = 0.f;

    if (blockIdx.x < 256) {
        int bd = (blockIdx.x & 15) * 32;
        int bu = (blockIdx.x >> 4) * 32;
        int tx = threadIdx.x & 31, ty = threadIdx.x >> 5;
        #pragma unroll
        for (int i = 0; i < 4; ++i)
            tile[ty + i * 8][tx] = f2bf(W1[(bd + ty + i * 8) * NU + bu + tx]);
        __syncthreads();
        #pragma unroll
        for (int i = 0; i < 4; ++i)
            w1t[(bu + ty + i * 8) * ND + bd + tx] = tile[tx][ty + i * 8];
    } else {
        int blk = blockIdx.x - 256;
        int b  = blk >> 3;
        int uc = (blk & 7) * 64;
        int ui = threadIdx.x & 63;
        int du = threadIdx.x >> 6;
        for (int i = threadIdx.x; i < ND; i += 256) h[i] = hidden[b * ND + i];
        __syncthreads();
        int u = uc + ui;
        float acc = 0.f;
        int d0 = du * 128;
        #pragma unroll 8
        for (int d = 0; d < 128; ++d) acc += h[d0 + d] * W2[(d0 + d) * NU + u];
        part[du][ui] = acc;
        __syncthreads();
        if (threadIdx.x < 64)
            projh[b * NU + u] = part[0][ui] + part[1][ui] + part[2][ui] + part[3][ui] + b2[u];
    }
}

// ---- logits partial: 128 rows x 128 U per block, K=512 in 8 phases ---------
// 32 KB LDS single-buffered -> 5 blocks/CU (20 waves/CU). 4 waves in 2x2:
// wave (wr,wc2) owns rows [wr*64,+64) x U [wc2*64,+64) (mt4 x nt4, acc 64).
// XCD-swizzled grid: the 4 utiles of an mtile are consecutive slots on ONE
// XCD -> per-phase A chunks hit that XCD's L2 (A fetched ~once from HBM).
__global__ __launch_bounds__(256, 4)
void k_logits(const float* __restrict__ feat, const u16* __restrict__ w1t,
              const float* __restrict__ b1, const float* __restrict__ projh,
              const float* __restrict__ V, float* __restrict__ logits) {
    __shared__ __align__(16) u16 aT[128 * BK];   // 16 KB
    __shared__ __align__(16) u16 bT[128 * BK];   // 16 KB

    const int xcd   = blockIdx.x & 7;
    const int g     = blockIdx.x >> 3;
    const int utile = g & 3;
    const int mtile = (g >> 2) * 8 + xcd;        // 0..511
    const int row0  = mtile * 128;
    const int uc    = utile * 128;
    const int b     = row0 >> 11;
    const int tid   = threadIdx.x;
    const int wave  = tid >> 6, lane = tid & 63;
    const int quad  = lane >> 4, col = lane & 15;
    const int wr    = wave >> 1, wc2 = wave & 1;

    float4v acc[4][4];
    #pragma unroll
    for (int mt = 0; mt < 4; ++mt)
        #pragma unroll
        for (int nt = 0; nt < 4; ++nt) acc[mt][nt] = (float4v)0.f;

    const float* fbase = feat + (long)row0 * ND;
    const u16*   wbase = w1t + uc * ND;

    for (int p = 0; p < 8; ++p) {
        const int k0 = p * BK;
        // stage B first: pure DMA, no register deps (128 rows x 64 k)
        #pragma unroll
        for (int j = 0; j < 4; ++j) {
            int s  = j * 256 + tid;
            int r  = s >> 3;
            int gc = (s & 7) ^ (r & 7);
            const u16* gp = wbase + (long)r * ND + k0 + gc * 8;
            u16* lp = &bT[(j * 256 + wave * 64) * 8];   // wave-uniform base
            __builtin_amdgcn_global_load_lds(
                (const __attribute__((address_space(1))) unsigned int*)gp,
                (__attribute__((address_space(3))) unsigned int*)lp, 16, 0, 0);
        }
        // stage A: 128 rows x 64 k fp32 -> bf16 (8 dwordx4 loads in flight)
        #pragma unroll
        for (int i = 0; i < 4; ++i) {
            int s = i * 256 + tid;
            int r = s >> 3, c = s & 7;
            const float* gp = fbase + (long)r * ND + k0 + c * 8;
            float4v f0 = *(const float4v*)gp;
            float4v f1 = *(const float4v*)(gp + 4);
            *(u16x8*)(&aT[r * BK + ((c ^ (r & 7)) * 8)]) = cvt8(f0, f1);
        }
        __syncthreads();

        #pragma unroll
        for (int ks = 0; ks < 2; ++ks) {
            bf16x8 af[4], bf[4];
            #pragma unroll
            for (int mt = 0; mt < 4; ++mt) {
                int ra = wr * 64 + mt * 16 + col;
                af[mt] = *(const bf16x8*)(&aT[ra * BK + (((ks * 4 + quad) ^ (ra & 7)) * 8)]);
            }
            #pragma unroll
            for (int nt = 0; nt < 4; ++nt) {
                int rb = wc2 * 64 + nt * 16 + col;
                bf[nt] = *(const bf16x8*)(&bT[rb * BK + (((ks * 4 + quad) ^ (rb & 7)) * 8)]);
            }
            #pragma unroll
            for (int nt = 0; nt < 4; ++nt)
                #pragma unroll
                for (int mt = 0; mt < 4; ++mt)
                    acc[mt][nt] = __builtin_amdgcn_mfma_f32_16x16x32_bf16(af[mt], bf[nt], acc[mt][nt], 0, 0, 0);
        }
        __syncthreads();
    }

    // epilogue: u = uc + wc2*64 + nt*16 + col
    float b1v[4], phv[4], Vv[4];
    #pragma unroll
    for (int nt = 0; nt < 4; ++nt) {
        int u = uc + wc2 * 64 + nt * 16 + col;
        b1v[nt] = b1[u];
        phv[nt] = projh[b * NU + u];
        Vv[nt]  = V[u];
    }

    float (*part)[128] = (float(*)[128])aT;   // [2][128] reuse, post-barrier
    #pragma unroll
    for (int mt = 0; mt < 4; ++mt) {
        #pragma unroll
        for (int rg = 0; rg < 4; ++rg) {
            float s = 0.f;
            #pragma unroll
            for (int nt = 0; nt < 4; ++nt) {
                float pv = acc[mt][nt][rg] + b1v[nt] + phv[nt];
                s += fast_tanh(pv) * Vv[nt];
            }
            s += __shfl_xor(s, 1);
            s += __shfl_xor(s, 2);
            s += __shfl_xor(s, 4);
            s += __shfl_xor(s, 8);
            if (col == 0) part[wc2][wr * 64 + mt * 16 + quad * 4 + rg] = s;
        }
    }
    __syncthreads();
    if (tid < 128)
        atomicAdd(&logits[row0 + tid], part[0][tid] + part[1][tid]);
}

// ---- fused softmax + context (fp32 features for accuracy) ------------------
__global__ void k_ctx(const float* __restrict__ feat, const float* __restrict__ logits,
                      float* __restrict__ attn, float* __restrict__ ctx) {
    const int b  = blockIdx.x >> 4;
    const int tc = blockIdx.x & 15;
    const int tid = threadIdx.x;
    __shared__ float wm[4], ws[4];
    __shared__ float sa[128];

    const float* lg = logits + b * NT;
    float lv[8];
    float m = -1e30f;
    #pragma unroll
    for (int i = 0; i < 8; ++i) { lv[i] = lg[tid + i * 256]; m = fmaxf(m, lv[i]); }
    for (int o = 1; o < 64; o <<= 1) m = fmaxf(m, __shfl_xor(m, o));
    if ((tid & 63) == 0) wm[tid >> 6] = m;
    __syncthreads();
    m = fmaxf(fmaxf(wm[0], wm[1]), fmaxf(wm[2], wm[3]));
    float ssum = 0.f;
    #pragma unroll
    for (int i = 0; i < 8; ++i) ssum += __expf(lv[i] - m);
    for (int o = 1; o < 64; o <<= 1) ssum += __shfl_xor(ssum, o);
    if ((tid & 63) == 0) ws[tid >> 6] = ssum;
    __syncthreads();
    float inv = 1.f / (ws[0] + ws[1] + ws[2] + ws[3]);

    if (tid < 128) {
        int t = tc * 128 + tid;
        float a = __expf(lg[t] - m) * inv;
        sa[tid] = a;
        attn[b * NT + t] = a;
    }
    __syncthreads();

    const float* fb = feat + ((long)b * NT + tc * 128) * ND + tid * 2;
    float ax = 0.f, ay = 0.f;
    #pragma unroll 16
    for (int t = 0; t < 128; ++t) {
        float a = sa[t];
        float2 f = *(const float2*)(fb + (long)t * ND);
        ax += a * f.x; ay += a * f.y;
    }
    atomicAdd(&ctx[b * ND + tid * 2],     ax);
    atomicAdd(&ctx[b * ND + tid * 2 + 1], ay);
}

extern "C" void kernel_launch(void* const* d_in, const int* in_sizes, int n_in,
                              void* d_out, int out_size, void* d_ws, size_t ws_size,
                              hipStream_t stream) {
    const float* feat   = (const float*)d_in[0];
    const float* hidden = (const float*)d_in[1];
    const float* W1     = (const float*)d_in[2];
    const float* b1     = (const float*)d_in[3];
    const float* W2     = (const float*)d_in[4];
    const float* b2     = (const float*)d_in[5];
    const float* V      = (const float*)d_in[6];
    // d_in[7] = bv: unused — softmax(x + bv) == softmax(x)

    float* out_ctx  = (float*)d_out;            // [32,512]
    float* out_attn = (float*)d_out + NB * ND;  // [32,2048,1]

    u16*   w1t    = (u16*)d_ws;                                          // 512 KB
    float* projh  = (float*)((char*)d_ws + 512 * 1024);                  // 64 KB
    float* logits = (float*)((char*)d_ws + 512 * 1024 + 64 * 1024);      // 256 KB

    k_prep  <<<512, 256, 0, stream>>>(W1, w1t, hidden, W2, b2, projh, logits, out_ctx);
    k_logits<<<2048, 256, 0, stream>>>(feat, w1t, b1, projh, V, logits);
    k_ctx   <<<512, 256, 0, stream>>>(feat, logits, out_attn, out_ctx);
}